// Round 5
// baseline (156.323 us; speedup 1.0000x reference)
//
#include <hip/hip_runtime.h>

// Per-clause softmax-attention pooling — 8-way token split, dual-state ILP.
// B=64, T=512, D=768, C=31 -> 32 segments/batch, 2048 segments total.
//
// One 256-thread block (4 waves) per segment. Each wave keeps TWO independent
// online-softmax states: A covers tokens == wave (mod 8), B covers tokens ==
// wave+4 (mod 8). The two dot/shfl-butterfly/exp chains are independent, so
// their ~350-cycle dependency latencies overlap (the shfl chain was the
// exposed serial cost in the 4-way version). Each hidden row is still read
// from HBM exactly once. Final merge: 8 partial (m, d, acc) states rescaled
// flash-style via LDS.
//
// m initialized to -1e30 (finite!) so exp(m - mn) is well-defined on the
// first token and for empty states (exp(-1e30 - M) == 0). Phantom-B
// iterations (tB >= L) are neutralized by predicating e_B to 0.

#define B_ 64
#define T_ 512
#define D_ 768
#define C_ 31
#define NSEG 32  // C+1

#define NEG_BIG (-1.0e30f)

__global__ __launch_bounds__(256) void seg_softmax_pool_split8(
    const float* __restrict__ hidden,    // [B, T, D]
    const int*   __restrict__ clause_b,  // [B, C]
    const float* __restrict__ w5,        // [D]
    const float* __restrict__ b5,        // [1]
    float*       __restrict__ out)       // [B, NSEG, D]
{
    const int tid  = threadIdx.x;
    const int wave = tid >> 6;
    const int lane = tid & 63;
    const int seg  = blockIdx.x;              // 0..2047
    const int b    = seg >> 5;                // / NSEG
    const int j    = seg & 31;                // % NSEG

    const int start = (j == 0)  ? 0  : clause_b[b * C_ + j - 1];
    const int end   = (j == C_) ? T_ : clause_b[b * C_ + j];
    const int L     = end - start;            // [2, 30] by construction

    // Lane owns dims d = c*256 + 4*lane + {0..3}, c in {0,1,2}.
    const int doff = 4 * lane;
    const float4 w0 = *(const float4*)(w5 + doff);
    const float4 w1 = *(const float4*)(w5 + doff + 256);
    const float4 w2 = *(const float4*)(w5 + doff + 512);
    const float bias = b5[0];

    const float* hseg = hidden + ((size_t)b * T_ + start) * D_ + doff;

    float4 A0 = make_float4(0.f, 0.f, 0.f, 0.f), A1 = A0, A2 = A0;
    float4 B0 = A0, B1 = A0, B2 = A0;
    float mA = NEG_BIG, dA = 0.0f;
    float mB = NEG_BIG, dB = 0.0f;

    for (int t = wave; t < L; t += 8) {
        const int  tB   = t + 4;
        const bool hasB = (tB < L);

        // Issue both rows' loads together (6 x 16B); B's addr clamped so the
        // load is always in-bounds, its value discarded via eB=0 when !hasB.
        const float* pA = hseg + (size_t)t * D_;
        const float* pB = hseg + (size_t)(hasB ? tB : t) * D_;
        const float4 cA0 = *(const float4*)(pA);
        const float4 cA1 = *(const float4*)(pA + 256);
        const float4 cA2 = *(const float4*)(pA + 512);
        const float4 cB0 = *(const float4*)(pB);
        const float4 cB1 = *(const float4*)(pB + 256);
        const float4 cB2 = *(const float4*)(pB + 512);

        // Two independent partial dots.
        float pa = cA0.x * w0.x + cA0.y * w0.y + cA0.z * w0.z + cA0.w * w0.w
                 + cA1.x * w1.x + cA1.y * w1.y + cA1.z * w1.z + cA1.w * w1.w
                 + cA2.x * w2.x + cA2.y * w2.y + cA2.z * w2.z + cA2.w * w2.w;
        float pb = cB0.x * w0.x + cB0.y * w0.y + cB0.z * w0.z + cB0.w * w0.w
                 + cB1.x * w1.x + cB1.y * w1.y + cB1.z * w1.z + cB1.w * w1.w
                 + cB2.x * w2.x + cB2.y * w2.y + cB2.z * w2.z + cB2.w * w2.w;

        // Interleaved butterflies — the two dependency chains overlap.
        #pragma unroll
        for (int off = 32; off > 0; off >>= 1) {
            pa += __shfl_xor(pa, off, 64);
            pb += __shfl_xor(pb, off, 64);
        }
        const float sA = pa + bias;
        const float sB = pb + bias;

        // Online update A.
        const float mnA = fmaxf(mA, sA);
        const float scA = __expf(mA - sA < 0.f ? mA - mnA : 0.f); // = expf(mA-mnA)
        const float eA  = __expf(sA - mnA);
        // Online update B (predicated).
        const float mnB = hasB ? fmaxf(mB, sB) : mB;
        const float scB = __expf(mB - mnB);
        const float eB  = hasB ? __expf(sB - mnB) : 0.0f;

        dA = fmaf(dA, scA, eA);
        dB = fmaf(dB, scB, eB);

        A0.x = fmaf(eA, cA0.x, A0.x * scA);  A0.y = fmaf(eA, cA0.y, A0.y * scA);
        A0.z = fmaf(eA, cA0.z, A0.z * scA);  A0.w = fmaf(eA, cA0.w, A0.w * scA);
        A1.x = fmaf(eA, cA1.x, A1.x * scA);  A1.y = fmaf(eA, cA1.y, A1.y * scA);
        A1.z = fmaf(eA, cA1.z, A1.z * scA);  A1.w = fmaf(eA, cA1.w, A1.w * scA);
        A2.x = fmaf(eA, cA2.x, A2.x * scA);  A2.y = fmaf(eA, cA2.y, A2.y * scA);
        A2.z = fmaf(eA, cA2.z, A2.z * scA);  A2.w = fmaf(eA, cA2.w, A2.w * scA);

        B0.x = fmaf(eB, cB0.x, B0.x * scB);  B0.y = fmaf(eB, cB0.y, B0.y * scB);
        B0.z = fmaf(eB, cB0.z, B0.z * scB);  B0.w = fmaf(eB, cB0.w, B0.w * scB);
        B1.x = fmaf(eB, cB1.x, B1.x * scB);  B1.y = fmaf(eB, cB1.y, B1.y * scB);
        B1.z = fmaf(eB, cB1.z, B1.z * scB);  B1.w = fmaf(eB, cB1.w, B1.w * scB);
        B2.x = fmaf(eB, cB2.x, B2.x * scB);  B2.y = fmaf(eB, cB2.y, B2.y * scB);
        B2.z = fmaf(eB, cB2.z, B2.z * scB);  B2.w = fmaf(eB, cB2.w, B2.w * scB);

        mA = mnA;
        mB = mnB;
    }

    // ---- Cross-wave merge: 8 partial states, flash-attention rescale ----
    __shared__ float s_acc[4][D_];   // 12 KB
    __shared__ float s_m[8], s_d[8];

    if (lane == 0) {
        s_m[wave]     = mA;  s_d[wave]     = dA;
        s_m[wave + 4] = mB;  s_d[wave + 4] = dB;
    }
    __syncthreads();

    float M = s_m[0];
    #pragma unroll
    for (int k = 1; k < 8; ++k) M = fmaxf(M, s_m[k]);
    float Tden = 0.0f;
    #pragma unroll
    for (int k = 0; k < 8; ++k) Tden += s_d[k] * __expf(s_m[k] - M);

    const float rsA = __expf(mA - M);   // 0 for empty state (m = -1e30)
    const float rsB = __expf(mB - M);

    float* dst = &s_acc[wave][doff];
    *(float4*)(dst)       = make_float4(fmaf(rsA, A0.x, rsB * B0.x), fmaf(rsA, A0.y, rsB * B0.y),
                                        fmaf(rsA, A0.z, rsB * B0.z), fmaf(rsA, A0.w, rsB * B0.w));
    *(float4*)(dst + 256) = make_float4(fmaf(rsA, A1.x, rsB * B1.x), fmaf(rsA, A1.y, rsB * B1.y),
                                        fmaf(rsA, A1.z, rsB * B1.z), fmaf(rsA, A1.w, rsB * B1.w));
    *(float4*)(dst + 512) = make_float4(fmaf(rsA, A2.x, rsB * B2.x), fmaf(rsA, A2.y, rsB * B2.y),
                                        fmaf(rsA, A2.z, rsB * B2.z), fmaf(rsA, A2.w, rsB * B2.w));
    __syncthreads();

    // Each thread owns dims d = tid, tid+256, tid+512 (coalesced dword stores).
    const float inv = 1.0f / Tden;
    float* op = out + ((size_t)b * NSEG + j) * D_;
    #pragma unroll
    for (int k = 0; k < 3; ++k) {
        const int d = tid + k * 256;
        const float v = s_acc[0][d] + s_acc[1][d] + s_acc[2][d] + s_acc[3][d];
        op[d] = v * inv;
    }
}

extern "C" void kernel_launch(void* const* d_in, const int* in_sizes, int n_in,
                              void* d_out, int out_size, void* d_ws, size_t ws_size,
                              hipStream_t stream) {
    const float* hidden   = (const float*)d_in[0];
    const int*   clause_b = (const int*)d_in[1];
    const float* w5       = (const float*)d_in[2];
    const float* b5       = (const float*)d_in[3];
    float*       out      = (float*)d_out;

    // One block per segment: 2048 blocks x 256 threads = 8192 waves.
    seg_softmax_pool_split8<<<B_ * NSEG, 256, 0, stream>>>(hidden, clause_b, w5, b5, out);
}

// Round 6
// 155.930 us; speedup vs baseline: 1.0025x; 1.0025x over previous
//
#include <hip/hip_runtime.h>

// Per-clause softmax-attention pooling — flash-style token-split version.
// B=64, T=512, D=768, C=31 -> 32 segments/batch, 2048 segments total.
//
// REVERT to round-4 structure (best measured: 155.6 us total). Round-5's
// dual-state ILP variant was neutral-to-worse: with ~24 waves/CU resident,
// TLP already covers HBM latency (need ~9 KB in flight per CU, have ~144 KB)
// — extra in-wave ILP only added VGPR pressure.
//
// One 256-thread block (4 waves) per segment. Wave w handles tokens
// t = w, w+4, ... with a PRIVATE online softmax (m, denom, acc[12]); each
// hidden row is read from HBM exactly once (100.7 MB total, ~16 us floor),
// score reduce is an in-wave 6-step shfl butterfly (no barriers in the token
// loop). Final merge across the 4 waves via LDS, flash-attention rescale:
//   M = max_w m_w;  T = sum_w d_w*exp(m_w-M);  out = sum_w exp(m_w-M)*acc_w / T

#define B_ 64
#define T_ 512
#define D_ 768
#define C_ 31
#define NSEG 32  // C+1

__global__ __launch_bounds__(256) void seg_softmax_pool_split(
    const float* __restrict__ hidden,    // [B, T, D]
    const int*   __restrict__ clause_b,  // [B, C]
    const float* __restrict__ w5,        // [D]
    const float* __restrict__ b5,        // [1]
    float*       __restrict__ out)       // [B, NSEG, D]
{
    const int tid  = threadIdx.x;
    const int wave = tid >> 6;
    const int lane = tid & 63;
    const int seg  = blockIdx.x;              // 0..2047
    const int b    = seg >> 5;                // / NSEG
    const int j    = seg & 31;                // % NSEG

    const int start = (j == 0)  ? 0  : clause_b[b * C_ + j - 1];
    const int end   = (j == C_) ? T_ : clause_b[b * C_ + j];
    const int L     = end - start;            // [2, 30] by construction

    // Lane owns dims d = c*256 + 4*lane + {0..3}, c in {0,1,2}.
    const int doff = 4 * lane;
    const float4 w0 = *(const float4*)(w5 + doff);
    const float4 w1 = *(const float4*)(w5 + doff + 256);
    const float4 w2 = *(const float4*)(w5 + doff + 512);
    const float bias = b5[0];

    const float* hseg = hidden + ((size_t)b * T_ + start) * D_ + doff;

    float4 a0 = make_float4(0.f, 0.f, 0.f, 0.f);
    float4 a1 = a0, a2 = a0;
    float m = -INFINITY, denom = 0.0f;

    // Prefetch this wave's first row (guarded).
    float4 c0 = a0, c1 = a0, c2 = a0;
    if (wave < L) {
        const float* p0 = hseg + (size_t)wave * D_;
        c0 = *(const float4*)(p0);
        c1 = *(const float4*)(p0 + 256);
        c2 = *(const float4*)(p0 + 512);
    }

    for (int t = wave; t < L; t += 4) {
        // Prefetch row t+4 while reducing row t (no barrier in the loop).
        float4 n0 = make_float4(0.f, 0.f, 0.f, 0.f), n1 = n0, n2 = n0;
        if (t + 4 < L) {
            const float* np = hseg + (size_t)(t + 4) * D_;
            n0 = *(const float4*)(np);
            n1 = *(const float4*)(np + 256);
            n2 = *(const float4*)(np + 512);
        }

        float p = c0.x * w0.x + c0.y * w0.y + c0.z * w0.z + c0.w * w0.w
                + c1.x * w1.x + c1.y * w1.y + c1.z * w1.z + c1.w * w1.w
                + c2.x * w2.x + c2.y * w2.y + c2.z * w2.z + c2.w * w2.w;
        #pragma unroll
        for (int off = 32; off > 0; off >>= 1)
            p += __shfl_xor(p, off, 64);
        const float s = p + bias;

        const float mn    = fmaxf(m, s);
        const float scale = __expf(m - mn);   // 0 on first token (m = -inf)
        const float e     = __expf(s - mn);
        denom = denom * scale + e;
        a0.x = a0.x * scale + e * c0.x;  a0.y = a0.y * scale + e * c0.y;
        a0.z = a0.z * scale + e * c0.z;  a0.w = a0.w * scale + e * c0.w;
        a1.x = a1.x * scale + e * c1.x;  a1.y = a1.y * scale + e * c1.y;
        a1.z = a1.z * scale + e * c1.z;  a1.w = a1.w * scale + e * c1.w;
        a2.x = a2.x * scale + e * c2.x;  a2.y = a2.y * scale + e * c2.y;
        a2.z = a2.z * scale + e * c2.z;  a2.w = a2.w * scale + e * c2.w;
        m = mn;
        c0 = n0; c1 = n1; c2 = n2;
    }

    // ---- Cross-wave merge (flash-attention rescale) ----
    __shared__ float s_acc[4][D_];   // 12 KB
    __shared__ float s_m[4], s_d[4];

    if (lane == 0) { s_m[wave] = m; s_d[wave] = denom; }
    __syncthreads();

    const float M = fmaxf(fmaxf(s_m[0], s_m[1]), fmaxf(s_m[2], s_m[3]));
    const float Tden = s_d[0] * __expf(s_m[0] - M) + s_d[1] * __expf(s_m[1] - M)
                     + s_d[2] * __expf(s_m[2] - M) + s_d[3] * __expf(s_m[3] - M);
    const float myscale = __expf(m - M);      // 0 for token-less waves (m=-inf)

    float* dst = &s_acc[wave][doff];
    *(float4*)(dst)       = make_float4(a0.x * myscale, a0.y * myscale, a0.z * myscale, a0.w * myscale);
    *(float4*)(dst + 256) = make_float4(a1.x * myscale, a1.y * myscale, a1.z * myscale, a1.w * myscale);
    *(float4*)(dst + 512) = make_float4(a2.x * myscale, a2.y * myscale, a2.z * myscale, a2.w * myscale);
    __syncthreads();

    // Each thread owns dims d = tid, tid+256, tid+512 (coalesced dword stores).
    const float inv = 1.0f / Tden;
    float* op = out + ((size_t)b * NSEG + j) * D_;
    #pragma unroll
    for (int k = 0; k < 3; ++k) {
        const int d = tid + k * 256;
        const float v = s_acc[0][d] + s_acc[1][d] + s_acc[2][d] + s_acc[3][d];
        op[d] = v * inv;
    }
}

extern "C" void kernel_launch(void* const* d_in, const int* in_sizes, int n_in,
                              void* d_out, int out_size, void* d_ws, size_t ws_size,
                              hipStream_t stream) {
    const float* hidden   = (const float*)d_in[0];
    const int*   clause_b = (const int*)d_in[1];
    const float* w5       = (const float*)d_in[2];
    const float* b5       = (const float*)d_in[3];
    float*       out      = (float*)d_out;

    // One block per segment: 2048 blocks x 256 threads = 8192 waves.
    seg_softmax_pool_split<<<B_ * NSEG, 256, 0, stream>>>(hidden, clause_b, w5, b5, out);
}